// Round 14
// baseline (147.318 us; speedup 1.0000x reference)
//
#include <hip/hip_runtime.h>

#define DIM    256
#define NCODES 1024
#define BATCH  16
#define SEQ    2048
#define NROWS  (BATCH * SEQ)   // 32768
#define NTHR   256

typedef short short8 __attribute__((ext_vector_type(8)));
typedef float f32x4 __attribute__((ext_vector_type(4)));

__device__ __forceinline__ float wave_reduce_sum(float s) {
#pragma unroll
  for (int off = 32; off > 0; off >>= 1) s += __shfl_down(s, off, 64);
  return s;
}

// round-to-nearest-even float -> bf16 (raw short)
__device__ __forceinline__ short f2bf(float f) {
  unsigned u = __builtin_bit_cast(unsigned, f);
  u = (u + 0x7fff + ((u >> 16) & 1)) >> 16;
  return (short)u;
}
__device__ __forceinline__ float bf2f(short s) {
  unsigned u = ((unsigned)(unsigned short)s) << 16;
  return __builtin_bit_cast(float, u);
}

// ---- small prep: B pack (blocks 0..63), mask/denom (64..79) ----
// bbuf: [(g128*8+s)*1024 + ((nb8*2+reg)*4+kgl)*16 + m] short8
//   code = g128*128 + nb8*16 + m ; dims = s*32 + kgl*8 + j ; reg0=hi reg1=lo
__global__ __launch_bounds__(NTHR) void k_prep(const float* __restrict__ cb,
                                               const float* __restrict__ mask,
                                               short8* __restrict__ bbuf,
                                               float* __restrict__ cbsq,
                                               float* __restrict__ denom,
                                               float* __restrict__ lsum) {
  const int bid = blockIdx.x;
  const int t = threadIdx.x;
  __shared__ float tile[16 * 257];
  if (bid < 64) {
    // ---- prep B: 16 codes per block ----
    const int nb = bid;
    const float* src = cb + (size_t)nb * 16 * DIM;
#pragma unroll
    for (int i = 0; i < 16; ++i) tile[i * 257 + t] = src[i * DIM + t];
    __syncthreads();
#pragma unroll
    for (int it = 0; it < 4; ++it) {
      const int idx = it * NTHR + t;
      const int kg = idx >> 4;
      const int m = idx & 15;
      const int reg = kg >> 5;
      const int sk = kg & 31;
      const int sg = sk >> 2;
      const int kgl = sk & 3;
      short8 v;
#pragma unroll
      for (int j = 0; j < 8; ++j) {
        const float w = tile[m * 257 + sk * 8 + j];
        const short h = f2bf(w);
        v[j] = reg ? f2bf(w - bf2f(h)) : h;
      }
      bbuf[(size_t)((nb >> 3) * 8 + sg) * 1024 +
           (((nb & 7) * 2 + reg) * 4 + kgl) * 16 + m] = v;
    }
    if (t < 16) {
      float s2 = 0.f;
      for (int c = 0; c < DIM; ++c) { const float w = tile[t * 257 + c]; s2 = fmaf(w, w, s2); }
      cbsq[nb * 16 + t] = s2;
    }
  } else {
    // ---- mask sums + zero loss accumulators ----
    const int b = bid - 64;
    float s = 0.f;
    for (int i = t; i < SEQ; i += NTHR) s += mask[b * SEQ + i];
    s = wave_reduce_sum(s);
    __shared__ float red[NTHR / 64];
    if ((t & 63) == 0) red[t >> 6] = s;
    __syncthreads();
    if (t == 0) { denom[b] = red[0] + red[1] + red[2] + red[3]; lsum[b] = 0.f; }
  }
}

// ---- mega kernel: in-kernel A split-convert + score vs ALL 1024 codes +
//      block-local argmin + gather + straight-through + masked MSE ----
// R13 structure with the block HALVED to 32 rows for occupancy:
// sA = 32 rows full-K hi/lo = 32 KB -> 4 blocks/CU = 16 waves/CU =
// 4 waves/SIMD (vs 2). Rationale: the compiler provably never pipelines
// global loads at source level (VGPR stayed 92 across R10-R13 attempts),
// so the ONLY latency-hiding mechanism is wave TLP -- double it.
// Per phase/wave: 8 B global loads (straight from L2-resident bbuf,
// lane-linear) + 4 A ds_reads + 24 MFMAs + raw s_barrier (pacing only;
// sA is read-only after the single fencing __syncthreads).
// __launch_bounds__(256,4) pins VGPR <= 128 so 16 waves/CU materializes.
// Per-(row,code) MFMA chain (hh,lh,hl per s, s ascending) and
// ascending-code argmin folds preserved -> outq bit-exact.
__global__ __launch_bounds__(NTHR, 4) void k_mega(const short8* __restrict__ bbuf,
                                                  const float* __restrict__ cbsq,
                                                  const float* __restrict__ feat,
                                                  const float* __restrict__ cb,
                                                  const float* __restrict__ mask,
                                                  float* __restrict__ outq,
                                                  float* __restrict__ lsum) {
  __shared__ short8 sA[2048];  // 32 KB: slot = s*256 + mi*128 + reg*64 + kgl*16 + m
  __shared__ float md[128];    // merge scratch: [4 waves][32 rows]
  __shared__ int mim[128];
  __shared__ int skid[32];
  __shared__ float red[4];
  const int t = threadIdx.x;
  const int w = t >> 6;
  const int lane = t & 63;
  const int l15 = lane & 15;
  const int quad = lane >> 4;
  const int blk = blockIdx.x;        // 1024 blocks x 32 rows
  const int row0 = blk * 32;

  // ---- phase 0: convert this block's 32 rows f32 -> hi/lo bf16 into sA ----
  // 1024 slots over 4 iterations; slot -> (s, rl, kgl); exact old expressions.
  {
    const float4* __restrict__ fsrc = (const float4*)feat;
#pragma unroll
    for (int it = 0; it < 4; ++it) {
      const int slot = it * NTHR + t;
      const int s = slot >> 7;         // 128 items per s (32 rows x 4 kgl)
      const int rl = (slot >> 2) & 31;
      const int kgl = slot & 3;
      const int row = row0 + rl;
      const size_t f4 = (size_t)row * 64 + s * 8 + kgl * 2;
      const float4 x0 = fsrc[f4];
      const float4 x1 = fsrc[f4 + 1];
      const float xs[8] = {x0.x, x0.y, x0.z, x0.w, x1.x, x1.y, x1.z, x1.w};
      short8 hi, lo;
#pragma unroll
      for (int j = 0; j < 8; ++j) {
        const short hh = f2bf(xs[j]);
        hi[j] = hh;
        lo[j] = f2bf(xs[j] - bf2f(hh));
      }
      const int mi = rl >> 4, m = rl & 15;
      sA[s * 256 + mi * 128 + 0 * 64 + kgl * 16 + m] = hi;
      sA[s * 256 + mi * 128 + 1 * 64 + kgl * 16 + m] = lo;
    }
  }
  __syncthreads();                   // the ONLY fencing barrier: sA ready

  float best[8];
  int bidx[8];
#pragma unroll
  for (int j = 0; j < 8; ++j) { best[j] = 3.4e38f; bidx[j] = 0; }

#pragma unroll 1
  for (int cg2 = 0; cg2 < 4; ++cg2) {   // 256-code groups
    f32x4 C[2][4];
#pragma unroll
    for (int mi = 0; mi < 2; ++mi)
#pragma unroll
      for (int ni = 0; ni < 4; ++ni) C[mi][ni] = (f32x4)0.f;

#pragma unroll
    for (int s = 0; s < 8; ++s) {
      __builtin_amdgcn_s_barrier();  // raw pacing barrier (no fence needed:
                                     // no LDS writes in the main loop)
      // ---- B fragments straight from global (L2-resident, lane-linear) ----
      // wave w covers codes cg2*256 + w*64 .. +63
      const short8* gB = bbuf + ((size_t)((cg2 * 2 + (w >> 1)) * 8 + s)) * 1024 +
                         (w & 1) * 512 + lane;
      short8 bh[4], bl[4];
#pragma unroll
      for (int ni = 0; ni < 4; ++ni) {
        bh[ni] = gB[ni * 128];
        bl[ni] = gB[ni * 128 + 64];
      }
      // ---- A fragments from LDS ----
      short8 ah[2], al[2];
#pragma unroll
      for (int mi = 0; mi < 2; ++mi) {
        ah[mi] = sA[s * 256 + mi * 128 + quad * 16 + l15];
        al[mi] = sA[s * 256 + mi * 128 + 64 + quad * 16 + l15];
      }
#pragma unroll
      for (int mi = 0; mi < 2; ++mi)
#pragma unroll
        for (int ni = 0; ni < 4; ++ni)
          C[mi][ni] = __builtin_amdgcn_mfma_f32_16x16x32_bf16(ah[mi], bh[ni], C[mi][ni], 0, 0, 0);
#pragma unroll
      for (int mi = 0; mi < 2; ++mi)
#pragma unroll
        for (int ni = 0; ni < 4; ++ni)
          C[mi][ni] = __builtin_amdgcn_mfma_f32_16x16x32_bf16(al[mi], bh[ni], C[mi][ni], 0, 0, 0);
#pragma unroll
      for (int mi = 0; mi < 2; ++mi)
#pragma unroll
        for (int ni = 0; ni < 4; ++ni)
          C[mi][ni] = __builtin_amdgcn_mfma_f32_16x16x32_bf16(ah[mi], bl[ni], C[mi][ni], 0, 0, 0);
    }

    // ---- fold this 256-code group into per-lane running argmin ----
    float cs[4];
#pragma unroll
    for (int ni = 0; ni < 4; ++ni) cs[ni] = cbsq[cg2 * 256 + w * 64 + ni * 16 + l15];
#pragma unroll
    for (int mi = 0; mi < 2; ++mi)
#pragma unroll
      for (int r = 0; r < 4; ++r) {
        const int j = mi * 4 + r;
#pragma unroll
        for (int ni = 0; ni < 4; ++ni) {
          const float d = fmaf(-2.f, C[mi][ni][r], cs[ni]);
          const int code = cg2 * 256 + w * 64 + ni * 16 + l15;
          if (d < best[j]) { best[j] = d; bidx[j] = code; }  // codes ascending
        }
      }
  }

  // ---- cross-lane argmin (over the 16 l15 code-columns) ----
#pragma unroll
  for (int m = 1; m <= 8; m <<= 1) {
#pragma unroll
    for (int j = 0; j < 8; ++j) {
      const float od = __shfl_xor(best[j], m, 64);
      const int oi = __shfl_xor(bidx[j], m, 64);
      if (od < best[j] || (od == best[j] && oi < bidx[j])) { best[j] = od; bidx[j] = oi; }
    }
  }

  // ---- cross-wave merge via LDS scratch ----
  if (l15 == 0) {
#pragma unroll
    for (int mi = 0; mi < 2; ++mi)
#pragma unroll
      for (int r = 0; r < 4; ++r) {
        const int row = mi * 16 + quad * 4 + r;
        md[w * 32 + row] = best[mi * 4 + r];
        mim[w * 32 + row] = bidx[mi * 4 + r];
      }
  }
  __syncthreads();
  if (t < 32) {
    float bd = md[t];
    int bi = mim[t];
#pragma unroll
    for (int ww = 1; ww < 4; ++ww) {
      const float od = md[ww * 32 + t];
      const int oi = mim[ww * 32 + t];
      if (od < bd || (od == bd && oi < bi)) { bd = od; bi = oi; }
    }
    skid[t] = bi;
  }
  __syncthreads();

  // ---- epilogue: gather + straight-through out + masked MSE ----
  const int wv = w;
  const int dg = lane;
  const int b = row0 >> 11;
  float acc = 0.f;
#pragma unroll
  for (int i = 0; i < 8; ++i) {
    const int r = wv * 8 + i;
    const size_t row = row0 + r;
    const int k = skid[r];
    const float4 q = ((const float4*)cb)[k * (DIM / 4) + dg];
    const float4 x = ((const float4*)feat)[row * (DIM / 4) + dg];
    float4 o;
    o.x = x.x + (q.x - x.x);
    o.y = x.y + (q.y - x.y);
    o.z = x.z + (q.z - x.z);
    o.w = x.w + (q.w - x.w);
    ((float4*)outq)[row * (DIM / 4) + dg] = o;
    const float m = mask[row];
    const float dx = x.x - q.x, dy = x.y - q.y, dz = x.z - q.z, dw = x.w - q.w;
    acc = fmaf(m, dx * dx + dy * dy + dz * dz + dw * dw, acc);
  }
  acc = wave_reduce_sum(acc);
  if (lane == 0) red[wv] = acc;
  __syncthreads();
  if (t == 0) atomicAdd(&lsum[b], red[0] + red[1] + red[2] + red[3]);
}

__global__ void k_final(const float* __restrict__ lsum,
                        const float* __restrict__ denom,
                        float* __restrict__ outl) {
  const int t = threadIdx.x;
  if (t < BATCH) {
    const float v = lsum[t] / denom[t];
    outl[t] = v;          // quant_loss
    outl[BATCH + t] = v;  // commit_loss (identical in forward)
  }
}

extern "C" void kernel_launch(void* const* d_in, const int* in_sizes, int n_in,
                              void* d_out, int out_size, void* d_ws, size_t ws_size,
                              hipStream_t stream) {
  const float* feat = (const float*)d_in[0];  // [16,2048,256]
  const float* mask = (const float*)d_in[1];  // [16,2048]
  const float* cb   = (const float*)d_in[2];  // [1024,256]
  float* out = (float*)d_out;

  char* p = (char*)d_ws;
  short8* bbuf = (short8*)p;                 p += (size_t)64 * 1024 * 16;    // 1.05 MB
  float* cbsq  = (float*)p;                  p += NCODES * 4;
  float* denom = (float*)p;                  p += BATCH * 4;
  float* lsum  = (float*)p;

  k_prep<<<64 + 16, NTHR, 0, stream>>>(cb, mask, bbuf, cbsq, denom, lsum);
  k_mega<<<NROWS / 32, NTHR, 0, stream>>>(bbuf, cbsq, feat, cb, mask, out, lsum);
  k_final<<<1, 64, 0, stream>>>(lsum, denom, out + (size_t)NROWS * DIM);
}

// Round 15
// 136.345 us; speedup vs baseline: 1.0805x; 1.0805x over previous
//
#include <hip/hip_runtime.h>

#define DIM    256
#define NCODES 1024
#define BATCH  16
#define SEQ    2048
#define NROWS  (BATCH * SEQ)   // 32768
#define NTHR   256

typedef short short8 __attribute__((ext_vector_type(8)));
typedef float f32x4 __attribute__((ext_vector_type(4)));

__device__ __forceinline__ float wave_reduce_sum(float s) {
#pragma unroll
  for (int off = 32; off > 0; off >>= 1) s += __shfl_down(s, off, 64);
  return s;
}

// round-to-nearest-even float -> bf16 (raw short)
__device__ __forceinline__ short f2bf(float f) {
  unsigned u = __builtin_bit_cast(unsigned, f);
  u = (u + 0x7fff + ((u >> 16) & 1)) >> 16;
  return (short)u;
}
__device__ __forceinline__ float bf2f(short s) {
  unsigned u = ((unsigned)(unsigned short)s) << 16;
  return __builtin_bit_cast(float, u);
}

// ---- small prep: B pack (blocks 0..63), mask/denom (64..79) ----
// bbuf: [(g128*8+s)*1024 + ((nb8*2+reg)*4+kgl)*16 + m] short8
//   code = g128*128 + nb8*16 + m ; dims = s*32 + kgl*8 + j ; reg0=hi reg1=lo
__global__ __launch_bounds__(NTHR) void k_prep(const float* __restrict__ cb,
                                               const float* __restrict__ mask,
                                               short8* __restrict__ bbuf,
                                               float* __restrict__ cbsq,
                                               float* __restrict__ denom,
                                               float* __restrict__ lsum) {
  const int bid = blockIdx.x;
  const int t = threadIdx.x;
  __shared__ float tile[16 * 257];
  if (bid < 64) {
    // ---- prep B: 16 codes per block ----
    const int nb = bid;
    const float* src = cb + (size_t)nb * 16 * DIM;
#pragma unroll
    for (int i = 0; i < 16; ++i) tile[i * 257 + t] = src[i * DIM + t];
    __syncthreads();
#pragma unroll
    for (int it = 0; it < 4; ++it) {
      const int idx = it * NTHR + t;
      const int kg = idx >> 4;
      const int m = idx & 15;
      const int reg = kg >> 5;
      const int sk = kg & 31;
      const int sg = sk >> 2;
      const int kgl = sk & 3;
      short8 v;
#pragma unroll
      for (int j = 0; j < 8; ++j) {
        const float w = tile[m * 257 + sk * 8 + j];
        const short h = f2bf(w);
        v[j] = reg ? f2bf(w - bf2f(h)) : h;
      }
      bbuf[(size_t)((nb >> 3) * 8 + sg) * 1024 +
           (((nb & 7) * 2 + reg) * 4 + kgl) * 16 + m] = v;
    }
    if (t < 16) {
      float s2 = 0.f;
      for (int c = 0; c < DIM; ++c) { const float w = tile[t * 257 + c]; s2 = fmaf(w, w, s2); }
      cbsq[nb * 16 + t] = s2;
    }
  } else {
    // ---- mask sums + zero loss accumulators ----
    const int b = bid - 64;
    float s = 0.f;
    for (int i = t; i < SEQ; i += NTHR) s += mask[b * SEQ + i];
    s = wave_reduce_sum(s);
    __shared__ float red[NTHR / 64];
    if ((t & 63) == 0) red[t >> 6] = s;
    __syncthreads();
    if (t == 0) { denom[b] = red[0] + red[1] + red[2] + red[3]; lsum[b] = 0.f; }
  }
}

// ---- mega kernel: in-kernel A split-convert + score vs ALL 1024 codes +
//      block-local argmin + gather + straight-through + masked MSE ----
// R13 base (64 rows, proven 61 us) with the barrier frequency HALVED:
// two K-steps (2 x 48 MFMAs, 16 B loads) per raw s_barrier. Evidence:
// R12 (+8% from widening) vs R14 (-19% from narrowing) shows the lever is
// straight-line work per barrier-free region -- the compiler pipelines
// loads WITHIN a basic block (sinks s+1 loads after s's MFMAs, whose ~230
// cyc cover L2 latency) but never across barriers. Pacing granularity of
// 16 events/block still keeps blocks phase-aligned for bbuf L2 residency
// (drift window 32 KB vs 4 MB L2).
// LDS = 64 KB sA + ~2.3 KB merge scratch -> 2 blocks/CU.
// Fragment values, hh/lh/hl chain per ascending s, argmin folds unchanged
// -> bit-exact.
__global__ __launch_bounds__(NTHR, 2) void k_mega(const short8* __restrict__ bbuf,
                                                  const float* __restrict__ cbsq,
                                                  const float* __restrict__ feat,
                                                  const float* __restrict__ cb,
                                                  const float* __restrict__ mask,
                                                  float* __restrict__ outq,
                                                  float* __restrict__ lsum) {
  __shared__ short8 sA[4096];  // 64 KB: slot = s*512 + mi*128 + reg*64 + kgl*16 + m
  __shared__ float md[256];    // merge scratch
  __shared__ int mim[256];
  __shared__ int skid[64];
  __shared__ float red[4];
  const int t = threadIdx.x;
  const int w = t >> 6;
  const int lane = t & 63;
  const int l15 = lane & 15;
  const int quad = lane >> 4;
  const int blk = blockIdx.x;        // 512 blocks x 64 rows
  const int row0 = blk * 64;

  // ---- phase 0: convert this block's 64 rows f32 -> hi/lo bf16 into sA ----
  {
    const float4* __restrict__ fsrc = (const float4*)feat;
    const int mi = w;
    const int kgl = quad;            // == (t>>4)&3
    const int m = l15;
    const int row = row0 + mi * 16 + m;
#pragma unroll
    for (int s = 0; s < 8; ++s) {
      const size_t f4 = (size_t)row * 64 + s * 8 + kgl * 2;
      const float4 x0 = fsrc[f4];
      const float4 x1 = fsrc[f4 + 1];
      const float xs[8] = {x0.x, x0.y, x0.z, x0.w, x1.x, x1.y, x1.z, x1.w};
      short8 hi, lo;
#pragma unroll
      for (int j = 0; j < 8; ++j) {
        const short hh = f2bf(xs[j]);
        hi[j] = hh;
        lo[j] = f2bf(xs[j] - bf2f(hh));
      }
      sA[s * 512 + mi * 128 + 0 * 64 + kgl * 16 + m] = hi;   // conflict-free b128
      sA[s * 512 + mi * 128 + 1 * 64 + kgl * 16 + m] = lo;
    }
  }
  __syncthreads();                   // the ONLY fencing barrier: sA ready

  float best[16];
  int bidx[16];
#pragma unroll
  for (int j = 0; j < 16; ++j) { best[j] = 3.4e38f; bidx[j] = 0; }

#pragma unroll 1
  for (int cg2 = 0; cg2 < 4; ++cg2) {   // 256-code groups
    f32x4 C[4][4];
#pragma unroll
    for (int mi = 0; mi < 4; ++mi)
#pragma unroll
      for (int ni = 0; ni < 4; ++ni) C[mi][ni] = (f32x4)0.f;

#pragma unroll
    for (int sp = 0; sp < 4; ++sp) {
      __builtin_amdgcn_s_barrier();  // raw pacing barrier, one per TWO K-steps
#pragma unroll
      for (int half = 0; half < 2; ++half) {
        const int s = sp * 2 + half;
        // ---- B fragments straight from global (L2-resident, lane-linear) ----
        const short8* gB = bbuf + ((size_t)((cg2 * 2 + (w >> 1)) * 8 + s)) * 1024 +
                           (w & 1) * 512 + lane;
        short8 bh[4], bl[4];
#pragma unroll
        for (int ni = 0; ni < 4; ++ni) {
          bh[ni] = gB[ni * 128];
          bl[ni] = gB[ni * 128 + 64];
        }
        // ---- A fragments from LDS ----
        short8 ah[4], al[4];
#pragma unroll
        for (int mi = 0; mi < 4; ++mi) {
          ah[mi] = sA[s * 512 + mi * 128 + quad * 16 + l15];
          al[mi] = sA[s * 512 + mi * 128 + 64 + quad * 16 + l15];
        }
#pragma unroll
        for (int mi = 0; mi < 4; ++mi)
#pragma unroll
          for (int ni = 0; ni < 4; ++ni)
            C[mi][ni] = __builtin_amdgcn_mfma_f32_16x16x32_bf16(ah[mi], bh[ni], C[mi][ni], 0, 0, 0);
#pragma unroll
        for (int mi = 0; mi < 4; ++mi)
#pragma unroll
          for (int ni = 0; ni < 4; ++ni)
            C[mi][ni] = __builtin_amdgcn_mfma_f32_16x16x32_bf16(al[mi], bh[ni], C[mi][ni], 0, 0, 0);
#pragma unroll
        for (int mi = 0; mi < 4; ++mi)
#pragma unroll
          for (int ni = 0; ni < 4; ++ni)
            C[mi][ni] = __builtin_amdgcn_mfma_f32_16x16x32_bf16(ah[mi], bl[ni], C[mi][ni], 0, 0, 0);
      }
    }

    // ---- fold this 256-code group into per-lane running argmin ----
    float cs[4];
#pragma unroll
    for (int ni = 0; ni < 4; ++ni) cs[ni] = cbsq[cg2 * 256 + w * 64 + ni * 16 + l15];
#pragma unroll
    for (int mi = 0; mi < 4; ++mi)
#pragma unroll
      for (int r = 0; r < 4; ++r) {
        const int j = mi * 4 + r;
#pragma unroll
        for (int ni = 0; ni < 4; ++ni) {
          const float d = fmaf(-2.f, C[mi][ni][r], cs[ni]);
          const int code = cg2 * 256 + w * 64 + ni * 16 + l15;
          if (d < best[j]) { best[j] = d; bidx[j] = code; }  // codes ascending
        }
      }
  }

  // ---- cross-lane argmin (over the 16 l15 code-columns) ----
#pragma unroll
  for (int m = 1; m <= 8; m <<= 1) {
#pragma unroll
    for (int j = 0; j < 16; ++j) {
      const float od = __shfl_xor(best[j], m, 64);
      const int oi = __shfl_xor(bidx[j], m, 64);
      if (od < best[j] || (od == best[j] && oi < bidx[j])) { best[j] = od; bidx[j] = oi; }
    }
  }

  // ---- cross-wave merge via LDS scratch ----
  if (l15 == 0) {
#pragma unroll
    for (int mi = 0; mi < 4; ++mi)
#pragma unroll
      for (int r = 0; r < 4; ++r) {
        const int row = mi * 16 + quad * 4 + r;
        md[w * 64 + row] = best[mi * 4 + r];
        mim[w * 64 + row] = bidx[mi * 4 + r];
      }
  }
  __syncthreads();
  if (t < 64) {
    float bd = md[t];
    int bi = mim[t];
#pragma unroll
    for (int ww = 1; ww < 4; ++ww) {
      const float od = md[ww * 64 + t];
      const int oi = mim[ww * 64 + t];
      if (od < bd || (od == bd && oi < bi)) { bd = od; bi = oi; }
    }
    skid[t] = bi;
  }
  __syncthreads();

  // ---- epilogue: gather + straight-through out + masked MSE ----
  const int wv = w;
  const int dg = lane;
  const int b = row0 >> 11;
  float acc = 0.f;
#pragma unroll
  for (int i = 0; i < 16; ++i) {
    const int r = wv * 16 + i;
    const size_t row = row0 + r;
    const int k = skid[r];
    const float4 q = ((const float4*)cb)[k * (DIM / 4) + dg];
    const float4 x = ((const float4*)feat)[row * (DIM / 4) + dg];
    float4 o;
    o.x = x.x + (q.x - x.x);
    o.y = x.y + (q.y - x.y);
    o.z = x.z + (q.z - x.z);
    o.w = x.w + (q.w - x.w);
    ((float4*)outq)[row * (DIM / 4) + dg] = o;
    const float m = mask[row];
    const float dx = x.x - q.x, dy = x.y - q.y, dz = x.z - q.z, dw = x.w - q.w;
    acc = fmaf(m, dx * dx + dy * dy + dz * dz + dw * dw, acc);
  }
  acc = wave_reduce_sum(acc);
  if (lane == 0) red[wv] = acc;
  __syncthreads();
  if (t == 0) atomicAdd(&lsum[b], red[0] + red[1] + red[2] + red[3]);
}

__global__ void k_final(const float* __restrict__ lsum,
                        const float* __restrict__ denom,
                        float* __restrict__ outl) {
  const int t = threadIdx.x;
  if (t < BATCH) {
    const float v = lsum[t] / denom[t];
    outl[t] = v;          // quant_loss
    outl[BATCH + t] = v;  // commit_loss (identical in forward)
  }
}

extern "C" void kernel_launch(void* const* d_in, const int* in_sizes, int n_in,
                              void* d_out, int out_size, void* d_ws, size_t ws_size,
                              hipStream_t stream) {
  const float* feat = (const float*)d_in[0];  // [16,2048,256]
  const float* mask = (const float*)d_in[1];  // [16,2048]
  const float* cb   = (const float*)d_in[2];  // [1024,256]
  float* out = (float*)d_out;

  char* p = (char*)d_ws;
  short8* bbuf = (short8*)p;                 p += (size_t)64 * 1024 * 16;    // 1.05 MB
  float* cbsq  = (float*)p;                  p += NCODES * 4;
  float* denom = (float*)p;                  p += BATCH * 4;
  float* lsum  = (float*)p;

  k_prep<<<64 + 16, NTHR, 0, stream>>>(cb, mask, bbuf, cbsq, denom, lsum);
  k_mega<<<NROWS / 64, NTHR, 0, stream>>>(bbuf, cbsq, feat, cb, mask, out, lsum);
  k_final<<<1, 64, 0, stream>>>(lsum, denom, out + (size_t)NROWS * DIM);
}